// Round 9
// baseline (1009.856 us; speedup 1.0000x reference)
//
#include <hip/hip_runtime.h>
#include <stdint.h>

typedef unsigned short u16;
typedef signed char i8;

#define MTOK 4096
#define CIN  3072
#define COUT 3072
#define RANK 32
#define NG   48         // K groups of 64 (== GROUP_SIZE == K of mfma_i32_16x16x64_i8)
#define RSA  3136       // byte row stride, xq (i8)
#define RSB  3136       // byte row stride, wq (i8)
#define LKSPLIT 16
#define LKC (CIN/LKSPLIT)   // 192
#define WROWS 6             // wdq rows per prep block (3072 / 512)

typedef __attribute__((ext_vector_type(8))) short bf16x8;
typedef __attribute__((ext_vector_type(4))) float f32x4;
typedef __attribute__((ext_vector_type(4))) int   i32x4;

__device__ __forceinline__ u16 f2bf(float f) {
  union { float f; unsigned u; } v; v.f = f;
  unsigned r = v.u + 0x7FFFu + ((v.u >> 16) & 1u);  // RNE
  return (u16)(r >> 16);
}

__device__ __forceinline__ void gload_lds16(const void* g, void* l) {
  __builtin_amdgcn_global_load_lds(
      (const __attribute__((address_space(1))) unsigned int*)g,
      (__attribute__((address_space(3))) unsigned int*)l, 16, 0, 0);
}

// ---------------------------------------------------------------------------
// R9: int8 GEMM path. x quantizes to int4 codes q in [-8,7]; w codes are
// qw-8 in [-8,7]. GROUP_SIZE=64 == K of mfma_i32_16x16x64_i8, so ONE i8 MFMA
// computes one quant group's dot EXACTLY in i32; the f32 fixup
// acc += (float)S * ascale[m,g]*ws[g,o] is then MORE accurate than the old
// bf16 path (which rounded x_dq/w_dq to bf16). Data volume halves
// everywhere (i8 vs bf16): LDS reads per FLOP halve, staged/HBM bytes halve.
// ---------------------------------------------------------------------------

// Prep: 512 uniform blocks; each does 6 w-rows (byte-pack) + one lora/quant
// panel (q->xq i8, ascale->asc, bf16 xs -> lora MFMA partial).
__global__ __launch_bounds__(256) void prep_kernel(
    const float* __restrict__ x, const float* __restrict__ smooth,
    const int* __restrict__ qw, const float* __restrict__ pd,
    const float* __restrict__ pu,
    i8* __restrict__ xq, i8* __restrict__ wq, float* __restrict__ asc,
    u16* __restrict__ pu_bf, float* __restrict__ lp)
{
  const int b = blockIdx.x;      // 0..511
  const int t = threadIdx.x;

  // ---- (a) weight codes: rows b*6 .. b*6+5 (qv-8 as i8) + pu_bf cast ----
#pragma unroll
  for (int r = 0; r < WROWS; ++r) {
    const int o = b * WROWS + r;
    const int4* qrow = (const int4*)(qw + (size_t)o * CIN);
    i8* orow = wq + (size_t)o * RSB;
#pragma unroll
    for (int p = 0; p < 3; ++p) {
      const int c4 = p * 256 + t;
      const int4 qv = qrow[c4];
      char4 ov;
      ov.x = (i8)(qv.x - 8);
      ov.y = (i8)(qv.y - 8);
      ov.z = (i8)(qv.z - 8);
      ov.w = (i8)(qv.w - 8);
      *(char4*)(orow + c4 * 4) = ov;
    }
  }
  if (t < WROWS * RANK) {
    const int o = b * WROWS + (t >> 5);
    pu_bf[(size_t)o * RANK + (t & 31)] = f2bf(pu[(size_t)o * RANK + (t & 31)]);
  }

  // ---- (b) lora/quant panel (m0..m0+128) x K-chunk kblk ----
  __shared__ __align__(16) u16 sA[128 * 64];
  __shared__ __align__(16) u16 sB[32 * 64];
  const int m0 = (b >> 4) * 128;        // 32 m-panels
  const int kblk = b & 15;              // 16 K-splits
  const int wave = t >> 6, lane = t & 63;
  const int lm = lane & 15, lkq = (lane >> 4) * 8;

  f32x4 acc[2][2];
  const f32x4 fz = {0.f, 0.f, 0.f, 0.f};
#pragma unroll
  for (int i = 0; i < 2; ++i)
#pragma unroll
    for (int j = 0; j < 2; ++j) acc[i][j] = fz;

  for (int kt = 0; kt < LKC / 64; ++kt) {
    const int k0 = kblk * LKC + kt * 64;
    const int g = kblk * 3 + kt;        // global group id
    const int col = (t & 15) * 4;       // 16 lanes x 4 = one 64-quant-group per row
#pragma unroll
    for (int it = 0; it < 8; ++it) {
      const int row = it * 16 + (t >> 4);
      const float4 xv = *(const float4*)(x + (size_t)(m0 + row) * CIN + k0 + col);
      const float4 sv = *(const float4*)(smooth + k0 + col);
      const float xs0 = xv.x / sv.x, xs1 = xv.y / sv.y;
      const float xs2 = xv.z / sv.z, xs3 = xv.w / sv.w;
      ushort4 ov;
      ov.x = f2bf(xs0); ov.y = f2bf(xs1); ov.z = f2bf(xs2); ov.w = f2bf(xs3);
      *(ushort4*)&sA[row * 64 + col] = ov;
      float a = fmaxf(fmaxf(fabsf(xs0), fabsf(xs1)), fmaxf(fabsf(xs2), fabsf(xs3)));
#pragma unroll
      for (int off = 1; off < 16; off <<= 1) a = fmaxf(a, __shfl_xor(a, off));
      const float ascale = a / 7.0f;
      const float qd = fmaxf(ascale, 1e-8f);
      // q = clip(round(xs/qd), -8, 7): EXACT same q as reference
      float q0 = fminf(fmaxf(rintf(xs0 / qd), -8.f), 7.f);
      float q1 = fminf(fmaxf(rintf(xs1 / qd), -8.f), 7.f);
      float q2 = fminf(fmaxf(rintf(xs2 / qd), -8.f), 7.f);
      float q3 = fminf(fmaxf(rintf(xs3 / qd), -8.f), 7.f);
      char4 oq;
      oq.x = (i8)(int)q0; oq.y = (i8)(int)q1;
      oq.z = (i8)(int)q2; oq.w = (i8)(int)q3;
      *(char4*)(xq + (size_t)(m0 + row) * RSA + k0 + col) = oq;
      if ((t & 15) == 0) asc[(size_t)g * MTOK + m0 + row] = ascale;
    }
#pragma unroll
    for (int i = 0; i < 8; ++i) {
      const int idx = i * 256 + t;
      const int k = idx >> 5, r = idx & 31;
      sB[r * 64 + k] = f2bf(pd[(size_t)(k0 + k) * RANK + r]);
    }
    __syncthreads();
#pragma unroll
    for (int kk = 0; kk < 2; ++kk) {
      const int ko = kk * 32 + lkq;
      bf16x8 af[2], bfr[2];
#pragma unroll
      for (int i = 0; i < 2; ++i)
        af[i] = *(const bf16x8*)&sA[(wave * 32 + i * 16 + lm) * 64 + ko];
#pragma unroll
      for (int j = 0; j < 2; ++j)
        bfr[j] = *(const bf16x8*)&sB[(j * 16 + lm) * 64 + ko];
#pragma unroll
      for (int i = 0; i < 2; ++i)
#pragma unroll
        for (int j = 0; j < 2; ++j)
          acc[i][j] = __builtin_amdgcn_mfma_f32_16x16x32_bf16(af[i], bfr[j], acc[i][j], 0, 0, 0);
    }
    __syncthreads();
  }
  float* lpk = lp + (size_t)kblk * MTOK * RANK;
#pragma unroll
  for (int i = 0; i < 2; ++i)
#pragma unroll
    for (int j = 0; j < 2; ++j) {
      const int col = j * 16 + lm;
      const int row0 = m0 + wave * 32 + i * 16 + (lane >> 4) * 4;
#pragma unroll
      for (int r = 0; r < 4; ++r)
        lpk[(size_t)(row0 + r) * RANK + col] = acc[i][j][r];
    }
}

// Reduce lora K-split partials -> bf16 lora_bf (M, 32).
__global__ __launch_bounds__(256) void lora_fix_kernel(
    const float* __restrict__ lp, u16* __restrict__ lora_bf)
{
  const int idx = blockIdx.x * 256 + threadIdx.x;   // MTOK*RANK
  const int m = idx >> 5, c = idx & 31;
  float s = 0.f;
#pragma unroll
  for (int k = 0; k < LKSPLIT; ++k) s += lp[((size_t)k * MTOK + m) * RANK + c];
  lora_bf[(size_t)m * RANK + c] = f2bf(s);
}

// ---------------------------------------------------------------------------
// Main GEMM (R9 int8): 256x192 tile, grid 256 (1/CU), 8 waves (4M x 2N),
// 48 K-tiles of BK=64 (= one quant group each), 3-buf rotation, one barrier
// per tile (R8 schedule kept — only dtype and fixup change).
//
// Per tile per wave: 4 A-frag + 6 B-frag ds_read_b128 (i8, 16B = K64 slice),
// 4 ascale ds_read_b128 (broadcast within 16-lane groups), 6 ws ds_read_b32
// (broadcast); 24 x mfma_i32_16x16x64_i8 with C=0 (exact group dots); f32
// fixup acc += cvt(S) * (ascale[row]*ws[col]).
//
// LDS rows are 64 B (half a bank wrap) -> granule (row&1, 16B-slot[1:0]);
// swizzle slot' = slot ^ ((row>>1)&3) with 16-lane frag rows = conflict-free
// (same derivation measured 0-conflict in R8 at identical 64-B rows).
// Involution applied to the stage SOURCE chunk; LDS dest linear.
//
// Stage loads per tile per wave: w0: A2+B1+ascale1 = 4; w1-3: A2+B1 = 3;
// w4-7: A2+B2 = 4. Boundary vmcnt(N) with per-wave N (wave-uniform branch)
// forces tile T+1 complete, leaves T+2 in flight. lgkmcnt(0) before each
// barrier (reads of buf X drain before the barrier releasing its overwrite).
//
// ws (wscales (G,C_out) f32) for this block's 192 cols x 48 groups is
// preloaded once into LDS (36 KB) in the prologue.
// LDS: A 3x16K=48K | B 3x12K=36K | ascale 3x1K=3K | ws 36K -> 123 KB.
// ---------------------------------------------------------------------------

#define LDSA   0
#define LDSB   49152
#define LDSASC 86016
#define LDSWS  89088
#define LDSTOT 125952

__device__ __forceinline__ void stage64(const i8* __restrict__ Aq,
                                        const i8* __restrict__ Bq,
                                        const float* __restrict__ ascm,
                                        char* lds, int g, int buf,
                                        int t, int wid) {
  // A: 256 rows x 64 B = 1024 16B-chunks, 2 per thread
#pragma unroll
  for (int r = 0; r < 2; ++r) {
    const int id = r * 512 + t;
    const int row = id >> 2, sl = id & 3;
    const int c16 = sl ^ ((row >> 1) & 3);      // source chunk (involution)
    gload_lds16(Aq + (size_t)row * RSA + g * 64 + c16 * 16,
                lds + LDSA + buf * 16384 + id * 16);
  }
  // B: 192 rows x 64 B = 768 chunks: all threads 1; waves 4-7 a 2nd.
  {
    const int row = t >> 2, sl = t & 3;
    const int c16 = sl ^ ((row >> 1) & 3);
    gload_lds16(Bq + (size_t)row * RSB + g * 64 + c16 * 16,
                lds + LDSB + buf * 12288 + t * 16);
  }
  if (wid >= 4) {                               // wave-uniform
    const int c = 256 + t;                      // t in [256,512) -> c in [512,768)
    const int row = c >> 2, sl = c & 3;
    const int c16 = sl ^ ((row >> 1) & 3);
    gload_lds16(Bq + (size_t)row * RSB + g * 64 + c16 * 16,
                lds + LDSB + buf * 12288 + c * 16);
  }
  // ascale: 256 f32 = 1 KB: wave 0 (64 lanes x 16 B)
  if (wid == 0) {
    gload_lds16(ascm + (size_t)g * MTOK + t * 4,
                lds + LDSASC + buf * 1024 + t * 16);
  }
}

#define RD_ALL(BUF, G) \
  _Pragma("unroll") for (int a_ = 0; a_ < 4; ++a_) { \
    const int rl = (a_ >> 1) * 128 + wm * 32 + (a_ & 1) * 16 + lm; \
    aF[a_] = *(const i32x4*)&lds[LDSA + (BUF) * 16384 + rl * 64 + \
                                 ((q4 ^ ((rl >> 1) & 3)) << 4)]; \
  } \
  _Pragma("unroll") for (int b_ = 0; b_ < 6; ++b_) { \
    const int rb = (b_ / 3) * 96 + wn * 48 + (b_ % 3) * 16 + lm; \
    bF[b_] = *(const i32x4*)&lds[LDSB + (BUF) * 12288 + rb * 64 + \
                                 ((q4 ^ ((rb >> 1) & 3)) << 4)]; \
  } \
  _Pragma("unroll") for (int a_ = 0; a_ < 4; ++a_) { \
    const int r0 = (a_ >> 1) * 128 + wm * 32 + (a_ & 1) * 16 + q4 * 4; \
    ascF[a_] = *(const f32x4*)&lds[LDSASC + (BUF) * 1024 + r0 * 4]; \
  } \
  _Pragma("unroll") for (int b_ = 0; b_ < 6; ++b_) { \
    const int cb = (b_ / 3) * 96 + wn * 48 + (b_ % 3) * 16 + lm; \
    wsF[b_] = *(const float*)&lds[LDSWS + (G) * 768 + cb * 4]; \
  }

#define MATH_ALL() \
  __builtin_amdgcn_s_setprio(1); \
  _Pragma("unroll") for (int a_ = 0; a_ < 4; ++a_) \
  _Pragma("unroll") for (int b_ = 0; b_ < 6; ++b_) { \
    const i32x4 S = __builtin_amdgcn_mfma_i32_16x16x64_i8(aF[a_], bF[b_], zi, 0, 0, 0); \
    const float w_ = wsF[b_]; \
    acc[a_][b_][0] += (float)S[0] * (ascF[a_][0] * w_); \
    acc[a_][b_][1] += (float)S[1] * (ascF[a_][1] * w_); \
    acc[a_][b_][2] += (float)S[2] * (ascF[a_][2] * w_); \
    acc[a_][b_][3] += (float)S[3] * (ascF[a_][3] * w_); \
  } \
  __builtin_amdgcn_s_setprio(0);

#define VMB() do { \
  if (wid == 0 || wid >= 4) asm volatile("s_waitcnt vmcnt(4)" ::: "memory"); \
  else                      asm volatile("s_waitcnt vmcnt(3)" ::: "memory"); \
} while (0)
#define VM0() asm volatile("s_waitcnt vmcnt(0)" ::: "memory")
#define LK0() asm volatile("s_waitcnt lgkmcnt(0)" ::: "memory")

// One K-tile. CB = compute buf, SB = stage buf, GC = compute group,
// GS = stage group.
#define TILEI(CB, SB, GC, GS, DOSTAGE, VMW, DOBAR) do { \
  if (DOSTAGE) stage64(Aq, Bq, ascm, lds, (GS), (SB), t, wid); \
  RD_ALL(CB, GC); \
  MATH_ALL(); \
  LK0(); \
  VMW; \
  if (DOBAR) { \
    __builtin_amdgcn_s_barrier(); \
    __builtin_amdgcn_sched_barrier(0); \
  } \
} while (0)

__global__ __launch_bounds__(512, 2) void gemm_kernel(
    const i8* __restrict__ xq, const i8* __restrict__ wq,
    const float* __restrict__ wsc, const float* __restrict__ asc,
    const u16* __restrict__ pu_bf, const u16* __restrict__ lora_bf,
    const float* __restrict__ bias, float* __restrict__ out)
{
  __shared__ __align__(16) char lds[LDSTOT];   // 123 KiB

  const int t = threadIdx.x;
  const int wid = t >> 6, lane = t & 63;
  const int wm = wid >> 1, wn = wid & 1;       // 4M x 2N wave grid
  const int lm = lane & 15, q4 = lane >> 4;

  // XCD swizzle: 256 = 8 XCDs x 32; each XCD gets 2 full M-rows of tiles.
  const int wg = blockIdx.x;
  const int swz = (wg & 7) * 32 + (wg >> 3);
  const int by = swz >> 4, bx = swz & 15;      // 16 x 16 tile grid
  const int m0 = by * 256, n0 = bx * 192;

  const i8* Aq = xq + (size_t)m0 * RSA;
  const i8* Bq = wq + (size_t)n0 * RSB;
  const float* ascm = asc + m0;

  f32x4 acc[4][6];
  const f32x4 fz = {0.f, 0.f, 0.f, 0.f};
#pragma unroll
  for (int i = 0; i < 4; ++i)
#pragma unroll
    for (int j = 0; j < 6; ++j) acc[i][j] = fz;

  i32x4 aF[4], bF[6];
  f32x4 ascF[4];
  float wsF[6];
  const i32x4 zi = {0, 0, 0, 0};

  // Prologue: preload ws (48 groups x 192 cols f32 = 2304 16B-chunks).
#pragma unroll
  for (int k = 0; k < 4; ++k) {
    const int id = k * 512 + t;
    const int gg = id / 48, off = id % 48;     // 48 chunks per group-row
    gload_lds16(wsc + (size_t)gg * COUT + n0 + off * 4,
                lds + LDSWS + gg * 768 + off * 16);
  }
  if (t < 256) {
    const int id = 2048 + t;
    const int gg = id / 48, off = id % 48;
    gload_lds16(wsc + (size_t)gg * COUT + n0 + off * 4,
                lds + LDSWS + gg * 768 + off * 16);
  }
  // Stage tiles 0 -> buf0, 1 -> buf1; VMB forces ws+tile0, leaves tile1.
  stage64(Aq, Bq, ascm, lds, 0, 0, t, wid);
  stage64(Aq, Bq, ascm, lds, 1, 1, t, wid);
  VMB();
  __builtin_amdgcn_s_barrier();
  __builtin_amdgcn_sched_barrier(0);

  // Main loop: tiles 0..44 (48 total); buf = g%3, stage g+2.
  for (int T = 0; T < 45; T += 3) {
    TILEI(0, 2, T + 0, T + 2, 1, VMB(), 1);
    TILEI(1, 0, T + 1, T + 3, 1, VMB(), 1);
    TILEI(2, 1, T + 2, T + 4, 1, VMB(), 1);
  }
  TILEI(0, 2, 45, 47, 1, VMB(), 1);   // tile 45, stage 47 -> buf 2
  TILEI(1, 0, 46, 0,  0, VM0(), 1);   // tile 46 (no stage; drain 47's loads)
  TILEI(2, 0, 47, 0,  0, (void)0, 0); // tile 47

  // ---- lora epilogue: acc += lora_act(256x32) . proj_up(192x32)^T ----
  // (bf16 16x16x32 MFMA: C/D layout is shape-determined == i8 16x16x64's)
  bf16x8 bl[6];
#pragma unroll
  for (int bb = 0; bb < 6; ++bb) {
    const int bcol = n0 + (bb / 3) * 96 + wn * 48 + (bb % 3) * 16 + lm;
    bl[bb] = *(const bf16x8*)(pu_bf + (size_t)bcol * RANK + q4 * 8);
  }
#pragma unroll
  for (int a = 0; a < 4; ++a) {
    const int arow = m0 + (a >> 1) * 128 + wm * 32 + (a & 1) * 16 + lm;
    const bf16x8 al = *(const bf16x8*)(lora_bf + (size_t)arow * RANK + q4 * 8);
#pragma unroll
    for (int bb = 0; bb < 6; ++bb)
      acc[a][bb] = __builtin_amdgcn_mfma_f32_16x16x32_bf16(al, bl[bb], acc[a][bb], 0, 0, 0);
  }

  // store: C/D layout col=lane&15, row=(lane>>4)*4+reg  [m89-verified]
#pragma unroll
  for (int bb = 0; bb < 6; ++bb) {
    const int col = n0 + (bb / 3) * 96 + wn * 48 + (bb % 3) * 16 + lm;
    const float bv = bias[col];
#pragma unroll
    for (int a = 0; a < 4; ++a) {
      const int row0 = m0 + (a >> 1) * 128 + wm * 32 + (a & 1) * 16 + q4 * 4;
#pragma unroll
      for (int r = 0; r < 4; ++r)
        out[(size_t)(row0 + r) * COUT + col] = acc[a][bb][r] + bv;
    }
  }
}

extern "C" void kernel_launch(void* const* d_in, const int* in_sizes, int n_in,
                              void* d_out, int out_size, void* d_ws, size_t ws_size,
                              hipStream_t stream) {
  const float* x      = (const float*)d_in[0];
  const int*   qw     = (const int*)d_in[1];
  const float* wsc    = (const float*)d_in[2];
  const float* smooth = (const float*)d_in[3];
  const float* pd     = (const float*)d_in[4];
  const float* pu     = (const float*)d_in[5];
  const float* bias   = (const float*)d_in[6];
  float* out = (float*)d_out;

  i8*    xq      = (i8*)d_ws;                              // 4096*3136 = 12.9 MB
  i8*    wq      = xq + (size_t)MTOK * RSA;                // 3072*3136 =  9.6 MB
  float* asc     = (float*)(wq + (size_t)COUT * RSB);      // 48*4096*4 = 786 KB
  u16*   pu_bf   = (u16*)(asc + (size_t)NG * MTOK);        // 3072*32*2 = 196 KB
  u16*   lora_bf = pu_bf + (size_t)COUT * RANK;            // 4096*32*2 = 262 KB
  float* lp      = (float*)(lora_bf + (size_t)MTOK * RANK);// 16*4096*32*4 = 8.4 MB

  prep_kernel<<<512, 256, 0, stream>>>(
      x, smooth, qw, pd, pu, xq, wq, asc, pu_bf, lp);
  lora_fix_kernel<<<MTOK * RANK / 256, 256, 0, stream>>>(lp, lora_bf);
  gemm_kernel<<<256, 512, 0, stream>>>(
      xq, wq, wsc, asc, pu_bf, lora_bf, bias, out);
}

// Round 11
// 984.280 us; speedup vs baseline: 1.0260x; 1.0260x over previous
//
#include <hip/hip_runtime.h>
#include <stdint.h>

typedef unsigned short u16;
typedef signed char i8;

#define MTOK 4096
#define CIN  3072
#define COUT 3072
#define RANK 32
#define NG   48         // K groups of 64 (== GROUP_SIZE == K of mfma_i32_16x16x64_i8)
#define RSA  3136       // byte row stride, xq (i8)
#define RSB  3136       // byte row stride, wq (i8)
#define LKSPLIT 16
#define LKC (CIN/LKSPLIT)   // 192
#define WROWS 6             // wdq rows per prep block (3072 / 512)

typedef __attribute__((ext_vector_type(8))) short bf16x8;
typedef __attribute__((ext_vector_type(4))) float f32x4;
typedef __attribute__((ext_vector_type(4))) int   i32x4;

__device__ __forceinline__ u16 f2bf(float f) {
  union { float f; unsigned u; } v; v.f = f;
  unsigned r = v.u + 0x7FFFu + ((v.u >> 16) & 1u);  // RNE
  return (u16)(r >> 16);
}

__device__ __forceinline__ void gload_lds16(const void* g, void* l) {
  __builtin_amdgcn_global_load_lds(
      (const __attribute__((address_space(1))) unsigned int*)g,
      (__attribute__((address_space(3))) unsigned int*)l, 16, 0, 0);
}

// ---------------------------------------------------------------------------
// R10 (resubmit after infra failure) = R9 int8 path + spill fix. R9 spilled
// ~60 VGPRs/thread to scratch (VGPR_Count=128 vs ~190 needed; FETCH/WRITE =
// 1.2/2.0 GB of scratch traffic; 855 us). Cause: __launch_bounds__(512, 2)
// second arg acting as min-BLOCKS-per-CU (CUDA semantics) -> 16 waves/CU ->
// 128-VGPR cap. Fix: (512, 1) + per-a_ batching of MFMA->fixup to bound S
// liveness.
// ---------------------------------------------------------------------------

// Prep: 512 uniform blocks; each does 6 w-rows (byte-pack) + one lora/quant
// panel (q->xq i8, ascale->asc, bf16 xs -> lora MFMA partial).
__global__ __launch_bounds__(256) void prep_kernel(
    const float* __restrict__ x, const float* __restrict__ smooth,
    const int* __restrict__ qw, const float* __restrict__ pd,
    const float* __restrict__ pu,
    i8* __restrict__ xq, i8* __restrict__ wq, float* __restrict__ asc,
    u16* __restrict__ pu_bf, float* __restrict__ lp)
{
  const int b = blockIdx.x;      // 0..511
  const int t = threadIdx.x;

  // ---- (a) weight codes: rows b*6 .. b*6+5 (qv-8 as i8) + pu_bf cast ----
#pragma unroll
  for (int r = 0; r < WROWS; ++r) {
    const int o = b * WROWS + r;
    const int4* qrow = (const int4*)(qw + (size_t)o * CIN);
    i8* orow = wq + (size_t)o * RSB;
#pragma unroll
    for (int p = 0; p < 3; ++p) {
      const int c4 = p * 256 + t;
      const int4 qv = qrow[c4];
      char4 ov;
      ov.x = (i8)(qv.x - 8);
      ov.y = (i8)(qv.y - 8);
      ov.z = (i8)(qv.z - 8);
      ov.w = (i8)(qv.w - 8);
      *(char4*)(orow + c4 * 4) = ov;
    }
  }
  if (t < WROWS * RANK) {
    const int o = b * WROWS + (t >> 5);
    pu_bf[(size_t)o * RANK + (t & 31)] = f2bf(pu[(size_t)o * RANK + (t & 31)]);
  }

  // ---- (b) lora/quant panel (m0..m0+128) x K-chunk kblk ----
  __shared__ __align__(16) u16 sA[128 * 64];
  __shared__ __align__(16) u16 sB[32 * 64];
  const int m0 = (b >> 4) * 128;        // 32 m-panels
  const int kblk = b & 15;              // 16 K-splits
  const int wave = t >> 6, lane = t & 63;
  const int lm = lane & 15, lkq = (lane >> 4) * 8;

  f32x4 acc[2][2];
  const f32x4 fz = {0.f, 0.f, 0.f, 0.f};
#pragma unroll
  for (int i = 0; i < 2; ++i)
#pragma unroll
    for (int j = 0; j < 2; ++j) acc[i][j] = fz;

  for (int kt = 0; kt < LKC / 64; ++kt) {
    const int k0 = kblk * LKC + kt * 64;
    const int g = kblk * 3 + kt;        // global group id
    const int col = (t & 15) * 4;       // 16 lanes x 4 = one 64-quant-group per row
#pragma unroll
    for (int it = 0; it < 8; ++it) {
      const int row = it * 16 + (t >> 4);
      const float4 xv = *(const float4*)(x + (size_t)(m0 + row) * CIN + k0 + col);
      const float4 sv = *(const float4*)(smooth + k0 + col);
      const float xs0 = xv.x / sv.x, xs1 = xv.y / sv.y;
      const float xs2 = xv.z / sv.z, xs3 = xv.w / sv.w;
      ushort4 ov;
      ov.x = f2bf(xs0); ov.y = f2bf(xs1); ov.z = f2bf(xs2); ov.w = f2bf(xs3);
      *(ushort4*)&sA[row * 64 + col] = ov;
      float a = fmaxf(fmaxf(fabsf(xs0), fabsf(xs1)), fmaxf(fabsf(xs2), fabsf(xs3)));
#pragma unroll
      for (int off = 1; off < 16; off <<= 1) a = fmaxf(a, __shfl_xor(a, off));
      const float ascale = a / 7.0f;
      const float qd = fmaxf(ascale, 1e-8f);
      // q = clip(round(xs/qd), -8, 7): EXACT same q as reference
      float q0 = fminf(fmaxf(rintf(xs0 / qd), -8.f), 7.f);
      float q1 = fminf(fmaxf(rintf(xs1 / qd), -8.f), 7.f);
      float q2 = fminf(fmaxf(rintf(xs2 / qd), -8.f), 7.f);
      float q3 = fminf(fmaxf(rintf(xs3 / qd), -8.f), 7.f);
      char4 oq;
      oq.x = (i8)(int)q0; oq.y = (i8)(int)q1;
      oq.z = (i8)(int)q2; oq.w = (i8)(int)q3;
      *(char4*)(xq + (size_t)(m0 + row) * RSA + k0 + col) = oq;
      if ((t & 15) == 0) asc[(size_t)g * MTOK + m0 + row] = ascale;
    }
#pragma unroll
    for (int i = 0; i < 8; ++i) {
      const int idx = i * 256 + t;
      const int k = idx >> 5, r = idx & 31;
      sB[r * 64 + k] = f2bf(pd[(size_t)(k0 + k) * RANK + r]);
    }
    __syncthreads();
#pragma unroll
    for (int kk = 0; kk < 2; ++kk) {
      const int ko = kk * 32 + lkq;
      bf16x8 af[2], bfr[2];
#pragma unroll
      for (int i = 0; i < 2; ++i)
        af[i] = *(const bf16x8*)&sA[(wave * 32 + i * 16 + lm) * 64 + ko];
#pragma unroll
      for (int j = 0; j < 2; ++j)
        bfr[j] = *(const bf16x8*)&sB[(j * 16 + lm) * 64 + ko];
#pragma unroll
      for (int i = 0; i < 2; ++i)
#pragma unroll
        for (int j = 0; j < 2; ++j)
          acc[i][j] = __builtin_amdgcn_mfma_f32_16x16x32_bf16(af[i], bfr[j], acc[i][j], 0, 0, 0);
    }
    __syncthreads();
  }
  float* lpk = lp + (size_t)kblk * MTOK * RANK;
#pragma unroll
  for (int i = 0; i < 2; ++i)
#pragma unroll
    for (int j = 0; j < 2; ++j) {
      const int col = j * 16 + lm;
      const int row0 = m0 + wave * 32 + i * 16 + (lane >> 4) * 4;
#pragma unroll
      for (int r = 0; r < 4; ++r)
        lpk[(size_t)(row0 + r) * RANK + col] = acc[i][j][r];
    }
}

// Reduce lora K-split partials -> bf16 lora_bf (M, 32).
__global__ __launch_bounds__(256) void lora_fix_kernel(
    const float* __restrict__ lp, u16* __restrict__ lora_bf)
{
  const int idx = blockIdx.x * 256 + threadIdx.x;   // MTOK*RANK
  const int m = idx >> 5, c = idx & 31;
  float s = 0.f;
#pragma unroll
  for (int k = 0; k < LKSPLIT; ++k) s += lp[((size_t)k * MTOK + m) * RANK + c];
  lora_bf[(size_t)m * RANK + c] = f2bf(s);
}

// ---------------------------------------------------------------------------
// Main GEMM (int8): 256x192 tile, grid 256 (1/CU), 8 waves (4M x 2N),
// 48 K-tiles of BK=64 (one quant group each), 3-buf rotation, one barrier
// per tile. Per-group dot is EXACT in i32 (mfma_i32_16x16x64_i8, C=0);
// f32 fixup acc += cvt(S) * ascale[row] * ws[col].
//
// LDS rows 64 B (half bank wrap) -> granule (row&1, slot[1:0]); swizzle
// slot' = slot ^ ((row>>1)&3) with 16-lane frag rows = conflict-free
// (R8/R9 measured 0). Involution on the stage SOURCE chunk; LDS dest linear.
//
// Stage loads/tile/wave: w0 4 (A2+B1+asc1), w1-3 3 (A2+B1), w4-7 4 (A2+B2).
// Boundary vmcnt(N) per wave-group forces tile T+1 complete, leaves T+2 in
// flight. lgkmcnt(0) before each barrier.
// LDS: A 3x16K | B 3x12K | asc 3x1K | ws 36K = 123 KB.
// ---------------------------------------------------------------------------

#define LDSA   0
#define LDSB   49152
#define LDSASC 86016
#define LDSWS  89088
#define LDSTOT 125952

__device__ __forceinline__ void stage64(const i8* __restrict__ Aq,
                                        const i8* __restrict__ Bq,
                                        const float* __restrict__ ascm,
                                        char* lds, int g, int buf,
                                        int t, int wid) {
  // A: 256 rows x 64 B = 1024 16B-chunks, 2 per thread
#pragma unroll
  for (int r = 0; r < 2; ++r) {
    const int id = r * 512 + t;
    const int row = id >> 2, sl = id & 3;
    const int c16 = sl ^ ((row >> 1) & 3);      // source chunk (involution)
    gload_lds16(Aq + (size_t)row * RSA + g * 64 + c16 * 16,
                lds + LDSA + buf * 16384 + id * 16);
  }
  // B: 192 rows x 64 B = 768 chunks: all threads 1; waves 4-7 a 2nd.
  {
    const int row = t >> 2, sl = t & 3;
    const int c16 = sl ^ ((row >> 1) & 3);
    gload_lds16(Bq + (size_t)row * RSB + g * 64 + c16 * 16,
                lds + LDSB + buf * 12288 + t * 16);
  }
  if (wid >= 4) {                               // wave-uniform
    const int c = 256 + t;                      // t in [256,512) -> c in [512,768)
    const int row = c >> 2, sl = c & 3;
    const int c16 = sl ^ ((row >> 1) & 3);
    gload_lds16(Bq + (size_t)row * RSB + g * 64 + c16 * 16,
                lds + LDSB + buf * 12288 + c * 16);
  }
  // ascale: 256 f32 = 1 KB: wave 0 (64 lanes x 16 B)
  if (wid == 0) {
    gload_lds16(ascm + (size_t)g * MTOK + t * 4,
                lds + LDSASC + buf * 1024 + t * 16);
  }
}

#define RD_ALL(BUF, G) \
  _Pragma("unroll") for (int a_ = 0; a_ < 4; ++a_) { \
    const int rl = (a_ >> 1) * 128 + wm * 32 + (a_ & 1) * 16 + lm; \
    aF[a_] = *(const i32x4*)&lds[LDSA + (BUF) * 16384 + rl * 64 + \
                                 ((q4 ^ ((rl >> 1) & 3)) << 4)]; \
  } \
  _Pragma("unroll") for (int b_ = 0; b_ < 6; ++b_) { \
    const int rb = (b_ / 3) * 96 + wn * 48 + (b_ % 3) * 16 + lm; \
    bF[b_] = *(const i32x4*)&lds[LDSB + (BUF) * 12288 + rb * 64 + \
                                 ((q4 ^ ((rb >> 1) & 3)) << 4)]; \
  } \
  _Pragma("unroll") for (int a_ = 0; a_ < 4; ++a_) { \
    const int r0 = (a_ >> 1) * 128 + wm * 32 + (a_ & 1) * 16 + q4 * 4; \
    ascF[a_] = *(const f32x4*)&lds[LDSASC + (BUF) * 1024 + r0 * 4]; \
  } \
  _Pragma("unroll") for (int b_ = 0; b_ < 6; ++b_) { \
    const int cb = (b_ / 3) * 96 + wn * 48 + (b_ % 3) * 16 + lm; \
    wsF[b_] = *(const float*)&lds[LDSWS + (G) * 768 + cb * 4]; \
  }

// Per-a_ batch: 6 MFMAs then their 6 fixups -> S liveness bounded at 24 regs.
#define MATH_ALL() \
  __builtin_amdgcn_s_setprio(1); \
  _Pragma("unroll") for (int a_ = 0; a_ < 4; ++a_) { \
    i32x4 S_[6]; \
    _Pragma("unroll") for (int b_ = 0; b_ < 6; ++b_) \
      S_[b_] = __builtin_amdgcn_mfma_i32_16x16x64_i8(aF[a_], bF[b_], zi, 0, 0, 0); \
    _Pragma("unroll") for (int b_ = 0; b_ < 6; ++b_) { \
      const float w_ = wsF[b_]; \
      acc[a_][b_][0] += (float)S_[b_][0] * (ascF[a_][0] * w_); \
      acc[a_][b_][1] += (float)S_[b_][1] * (ascF[a_][1] * w_); \
      acc[a_][b_][2] += (float)S_[b_][2] * (ascF[a_][2] * w_); \
      acc[a_][b_][3] += (float)S_[b_][3] * (ascF[a_][3] * w_); \
    } \
  } \
  __builtin_amdgcn_s_setprio(0);

#define VMB() do { \
  if (wid == 0 || wid >= 4) asm volatile("s_waitcnt vmcnt(4)" ::: "memory"); \
  else                      asm volatile("s_waitcnt vmcnt(3)" ::: "memory"); \
} while (0)
#define VM0() asm volatile("s_waitcnt vmcnt(0)" ::: "memory")
#define LK0() asm volatile("s_waitcnt lgkmcnt(0)" ::: "memory")

// One K-tile. CB = compute buf, SB = stage buf, GC = compute group,
// GS = stage group.
#define TILEI(CB, SB, GC, GS, DOSTAGE, VMW, DOBAR) do { \
  if (DOSTAGE) stage64(Aq, Bq, ascm, lds, (GS), (SB), t, wid); \
  RD_ALL(CB, GC); \
  MATH_ALL(); \
  LK0(); \
  VMW; \
  if (DOBAR) { \
    __builtin_amdgcn_s_barrier(); \
    __builtin_amdgcn_sched_barrier(0); \
  } \
} while (0)

__global__ __launch_bounds__(512, 1) void gemm_kernel(
    const i8* __restrict__ xq, const i8* __restrict__ wq,
    const float* __restrict__ wsc, const float* __restrict__ asc,
    const u16* __restrict__ pu_bf, const u16* __restrict__ lora_bf,
    const float* __restrict__ bias, float* __restrict__ out)
{
  __shared__ __align__(16) char lds[LDSTOT];   // 123 KiB

  const int t = threadIdx.x;
  const int wid = t >> 6, lane = t & 63;
  const int wm = wid >> 1, wn = wid & 1;       // 4M x 2N wave grid
  const int lm = lane & 15, q4 = lane >> 4;

  // XCD swizzle: 256 = 8 XCDs x 32; each XCD gets 2 full M-rows of tiles.
  const int wg = blockIdx.x;
  const int swz = (wg & 7) * 32 + (wg >> 3);
  const int by = swz >> 4, bx = swz & 15;      // 16 x 16 tile grid
  const int m0 = by * 256, n0 = bx * 192;

  const i8* Aq = xq + (size_t)m0 * RSA;
  const i8* Bq = wq + (size_t)n0 * RSB;
  const float* ascm = asc + m0;

  f32x4 acc[4][6];
  const f32x4 fz = {0.f, 0.f, 0.f, 0.f};
#pragma unroll
  for (int i = 0; i < 4; ++i)
#pragma unroll
    for (int j = 0; j < 6; ++j) acc[i][j] = fz;

  i32x4 aF[4], bF[6];
  f32x4 ascF[4];
  float wsF[6];
  const i32x4 zi = {0, 0, 0, 0};

  // Prologue: preload ws (48 groups x 192 cols f32 = 2304 16B-chunks).
#pragma unroll
  for (int k = 0; k < 4; ++k) {
    const int id = k * 512 + t;
    const int gg = id / 48, off = id % 48;     // 48 chunks per group-row
    gload_lds16(wsc + (size_t)gg * COUT + n0 + off * 4,
                lds + LDSWS + gg * 768 + off * 16);
  }
  if (t < 256) {
    const int id = 2048 + t;
    const int gg = id / 48, off = id % 48;
    gload_lds16(wsc + (size_t)gg * COUT + n0 + off * 4,
                lds + LDSWS + gg * 768 + off * 16);
  }
  // Stage tiles 0 -> buf0, 1 -> buf1; VMB forces ws+tile0, leaves tile1.
  stage64(Aq, Bq, ascm, lds, 0, 0, t, wid);
  stage64(Aq, Bq, ascm, lds, 1, 1, t, wid);
  VMB();
  __builtin_amdgcn_s_barrier();
  __builtin_amdgcn_sched_barrier(0);

  // Main loop: tiles 0..44 (48 total); buf = g%3, stage g+2.
  for (int T = 0; T < 45; T += 3) {
    TILEI(0, 2, T + 0, T + 2, 1, VMB(), 1);
    TILEI(1, 0, T + 1, T + 3, 1, VMB(), 1);
    TILEI(2, 1, T + 2, T + 4, 1, VMB(), 1);
  }
  TILEI(0, 2, 45, 47, 1, VMB(), 1);   // tile 45, stage 47 -> buf 2
  TILEI(1, 0, 46, 0,  0, VM0(), 1);   // tile 46 (no stage; drain 47's loads)
  TILEI(2, 0, 47, 0,  0, (void)0, 0); // tile 47

  // ---- lora epilogue: acc += lora_act(256x32) . proj_up(192x32)^T ----
  // (bf16 16x16x32 MFMA: C/D layout is shape-determined == i8 16x16x64's)
  bf16x8 bl[6];
#pragma unroll
  for (int bb = 0; bb < 6; ++bb) {
    const int bcol = n0 + (bb / 3) * 96 + wn * 48 + (bb % 3) * 16 + lm;
    bl[bb] = *(const bf16x8*)(pu_bf + (size_t)bcol * RANK + q4 * 8);
  }
#pragma unroll
  for (int a = 0; a < 4; ++a) {
    const int arow = m0 + (a >> 1) * 128 + wm * 32 + (a & 1) * 16 + lm;
    const bf16x8 al = *(const bf16x8*)(lora_bf + (size_t)arow * RANK + q4 * 8);
#pragma unroll
    for (int bb = 0; bb < 6; ++bb)
      acc[a][bb] = __builtin_amdgcn_mfma_f32_16x16x32_bf16(al, bl[bb], acc[a][bb], 0, 0, 0);
  }

  // store: C/D layout col=lane&15, row=(lane>>4)*4+reg  [m89-verified]
#pragma unroll
  for (int bb = 0; bb < 6; ++bb) {
    const int col = n0 + (bb / 3) * 96 + wn * 48 + (bb % 3) * 16 + lm;
    const float bv = bias[col];
#pragma unroll
    for (int a = 0; a < 4; ++a) {
      const int row0 = m0 + (a >> 1) * 128 + wm * 32 + (a & 1) * 16 + q4 * 4;
#pragma unroll
      for (int r = 0; r < 4; ++r)
        out[(size_t)(row0 + r) * COUT + col] = acc[a][bb][r] + bv;
    }
  }
}

extern "C" void kernel_launch(void* const* d_in, const int* in_sizes, int n_in,
                              void* d_out, int out_size, void* d_ws, size_t ws_size,
                              hipStream_t stream) {
  const float* x      = (const float*)d_in[0];
  const int*   qw     = (const int*)d_in[1];
  const float* wsc    = (const float*)d_in[2];
  const float* smooth = (const float*)d_in[3];
  const float* pd     = (const float*)d_in[4];
  const float* pu     = (const float*)d_in[5];
  const float* bias   = (const float*)d_in[6];
  float* out = (float*)d_out;

  i8*    xq      = (i8*)d_ws;                              // 4096*3136 = 12.9 MB
  i8*    wq      = xq + (size_t)MTOK * RSA;                // 3072*3136 =  9.6 MB
  float* asc     = (float*)(wq + (size_t)COUT * RSB);      // 48*4096*4 = 786 KB
  u16*   pu_bf   = (u16*)(asc + (size_t)NG * MTOK);        // 3072*32*2 = 196 KB
  u16*   lora_bf = pu_bf + (size_t)COUT * RANK;            // 4096*32*2 = 262 KB
  float* lp      = (float*)(lora_bf + (size_t)MTOK * RANK);// 16*4096*32*4 = 8.4 MB

  prep_kernel<<<512, 256, 0, stream>>>(
      x, smooth, qw, pd, pu, xq, wq, asc, pu_bf, lp);
  lora_fix_kernel<<<MTOK * RANK / 256, 256, 0, stream>>>(lp, lora_bf);
  gemm_kernel<<<256, 512, 0, stream>>>(
      xq, wq, wsc, asc, pu_bf, lora_bf, bias, out);
}